// Round 17
// baseline (1024.611 us; speedup 1.0000x reference)
//
#include <hip/hip_runtime.h>
#include <hip/hip_bf16.h>
#include <stdint.h>

#define T_TOK 4096
#define H_DIM 2048
#define I_DIM 1024
#define NEXP  16
#define NROWS 16384

typedef short bf16x8 __attribute__((ext_vector_type(8)));
typedef float f32x4  __attribute__((ext_vector_type(4)));
typedef unsigned short u16;
typedef unsigned short u16x8 __attribute__((ext_vector_type(8)));

__device__ __forceinline__ u16 f2b(float f) {
  union { __hip_bfloat16 h; u16 u; } cv;
  cv.h = __float2bfloat16(f);
  return cv.u;
}

__device__ __forceinline__ void gload16(const void* g, void* l) {
  __builtin_amdgcn_global_load_lds((const __attribute__((address_space(1))) void*)g,
                                   (__attribute__((address_space(3))) void*)l, 16, 0, 0);
}

// 128-aligned prefix base of expert e, recomputed from counts (replaces prefix kernel)
__device__ __forceinline__ int rowbase_of(const int* __restrict__ counts, int e) {
  int acc = 0;
  for (int i = 0; i < e && i < NEXP; ++i) acc += (counts[i] + 127) & ~127;
  return acc;
}

// convert 8 fp32 (two 16B LDS chunks, possibly non-adjacent) -> bf16x8 fragment
__device__ __forceinline__ bf16x8 cvt_frag2(const float* pLo, const float* pHi) {
  f32x4 v0 = *(const f32x4*)pLo;
  f32x4 v1 = *(const f32x4*)pHi;
  bf16x8 o;
  o[0] = (short)f2b(v0[0]); o[1] = (short)f2b(v0[1]);
  o[2] = (short)f2b(v0[2]); o[3] = (short)f2b(v0[3]);
  o[4] = (short)f2b(v1[0]); o[5] = (short)f2b(v1[1]);
  o[6] = (short)f2b(v1[2]); o[7] = (short)f2b(v1[3]);
  return o;
}

// ---------------- router: fp64 logits, top-2, renormalized; also emits x_bf ----------------
__global__ __launch_bounds__(256) void router_kernel(const float* __restrict__ x,
                                                     const float* __restrict__ gw,
                                                     int* __restrict__ sel,
                                                     float* __restrict__ selw,
                                                     int* __restrict__ counts,
                                                     u16* __restrict__ x_bf) {
  int t = blockIdx.x;
  int tid = threadIdx.x;
  const float* xr = x + (size_t)t * H_DIM;
  double p[NEXP];
#pragma unroll
  for (int e = 0; e < NEXP; ++e) p[e] = 0.0;
  bf16x8 xs;
#pragma unroll
  for (int j = 0; j < 8; ++j) {
    int h = tid * 8 + j;
    float xf = xr[h];
    xs[j] = (short)f2b(xf);
    double xv = (double)xf;
#pragma unroll
    for (int e = 0; e < NEXP; ++e) p[e] += xv * (double)gw[e * H_DIM + h];
  }
  *(bf16x8*)(x_bf + (size_t)t * H_DIM + tid * 8) = xs;  // fused x cvt
#pragma unroll
  for (int e = 0; e < NEXP; ++e) {
#pragma unroll
    for (int off = 32; off > 0; off >>= 1) p[e] += __shfl_down(p[e], off);
  }
  __shared__ double sm[4][NEXP];
  int w = tid >> 6;
  if ((tid & 63) == 0) {
#pragma unroll
    for (int e = 0; e < NEXP; ++e) sm[w][e] = p[e];
  }
  __syncthreads();
  if (tid == 0) {
    double l0 = -1e300, l1 = -1e300;
    int e0 = 0, e1 = 0;
    for (int e = 0; e < NEXP; ++e) {
      double v = sm[0][e] + sm[1][e] + sm[2][e] + sm[3][e];
      if (v > l0) { l1 = l0; e1 = e0; l0 = v; e0 = e; }
      else if (v > l1) { l1 = v; e1 = e; }
    }
    double w0 = 1.0 / (1.0 + exp(l1 - l0));
    sel[t * 2 + 0] = e0;
    sel[t * 2 + 1] = e1;
    selw[t * 2 + 0] = (float)w0;
    selw[t * 2 + 1] = (float)(1.0 - w0);
    atomicAdd(&counts[e0], 1);
    atomicAdd(&counts[e1], 1);
  }
}

// ---------------- scatter tokens into packed per-expert row lists ----------------
__global__ __launch_bounds__(256) void scatter_kernel(const int* __restrict__ sel,
                                                      const float* __restrict__ selw,
                                                      const int* __restrict__ counts,
                                                      int* __restrict__ cursor,
                                                      int* __restrict__ tok_of_row,
                                                      float* __restrict__ coef_of_row,
                                                      int* __restrict__ row_of_tok) {
  int idx = blockIdx.x * 256 + threadIdx.x;
  if (idx < T_TOK * 2) {
    int t = idx >> 1;
    int e = sel[idx];
    int slot = atomicAdd(&cursor[e], 1);
    int row = rowbase_of(counts, e) + slot;
    tok_of_row[row] = t;
    coef_of_row[row] = selw[idx];
    row_of_tok[idx] = row;
  } else if (idx < T_TOK * 3) {
    int t = idx - T_TOK * 2;
    int sb = rowbase_of(counts, NEXP);
    tok_of_row[sb + t] = t;
    coef_of_row[sb + t] = 1.0f;
  }
}

// =================================================================
// GEMM1 (R14/R16-verified, fp32-B-direct m97 structure) + fused W2 cvt.
// Grid (rt=32, nt=16, e+1): rt FASTEST so the 32 blocks sharing one W1
// B-panel (1MB) are temporally adjacent -> L2/L3-hit B loads, shorter drain.
// z=0 blocks convert w2/sd_w -> W2cat bf16 (rides gemm1's idle HBM BW).
// 256 thr / 4 waves (2x2), tile 128x128, BK=64, LDS ~49KB -> 3 blocks/CU.
// A swizzle (0 conflicts): chunk c(8 bf16) -> row=c>>3,
//   koff=((c&7)*8)^((r&7)<<3); read (ks*32+hi*8)^((row&7)<<3).
// B fp32 swizzle (0 conflicts): chunk c(4 f32) -> row=c>>4,
//   src elem off=((c&15)^(r&15))*4; read slots s0=(ks*8+hi*2)^(r&15), s0^1.
// =================================================================
__global__ __launch_bounds__(256, 3) void gemm1_kernel(
    const u16* __restrict__ x_bf, const float* __restrict__ w1,
    const float* __restrict__ sg_w,
    const float* __restrict__ b1, const float* __restrict__ sg_b,
    const int* __restrict__ tok_of_row, const int* __restrict__ counts,
    u16* __restrict__ abuf,
    const float* __restrict__ w2, const float* __restrict__ sd_w,
    u16* __restrict__ W2cat) {
  int tid = threadIdx.x;

  if (blockIdx.z == 0) {
    // ---- W2/sd_w fp32 -> bf16 cvt, grid-stride over 512 blocks ----
    const int N2 = 16 * 2048 * 1024 / 8;  // w2 in 8-float units
    const int N3 = 2048 * 1024 / 8;       // sd_w
    int lin = blockIdx.y * 32 + blockIdx.x;          // [0,512)
    int gid = lin * 256 + tid;
    int stride = 512 * 256;
    u16x8* dst = (u16x8*)W2cat;
    for (int i = gid; i < N2 + N3; i += stride) {
      const float4* s = (i < N2) ? ((const float4*)w2 + 2 * (size_t)i)
                                 : ((const float4*)sd_w + 2 * (size_t)(i - N2));
      float4 v0 = s[0];
      float4 v1 = s[1];
      u16x8 o;
      o[0] = f2b(v0.x); o[1] = f2b(v0.y); o[2] = f2b(v0.z); o[3] = f2b(v0.w);
      o[4] = f2b(v1.x); o[5] = f2b(v1.y); o[6] = f2b(v1.z); o[7] = f2b(v1.w);
      dst[i] = o;
    }
    return;
  }

  int rt = blockIdx.x, nt = blockIdx.y, e = blockIdx.z - 1;
  int n_e = (e < NEXP) ? counts[e] : T_TOK;
  if (rt * 128 >= n_e) return;
  int rbase = rowbase_of(counts, e);
  int n_valid = n_e - rt * 128;
  if (n_valid > 128) n_valid = 128;

  __shared__ short As[128 * 64];   // bf16, swizzled
  __shared__ float Bsf[128 * 64];  // fp32, swizzled
  __shared__ int Ts[128];

  if (tid < 128)
    Ts[tid] = (rt * 128 + tid < n_e) ? tok_of_row[rbase + rt * 128 + tid] : 0;
  __syncthreads();

  int wavebase = tid & 0xC0;
  const u16* srcA[4];
  short* dstA[4];
#pragma unroll
  for (int p = 0; p < 4; ++p) {
    int c = p * 256 + tid;
    int r = c >> 3;
    int koff = ((c & 7) * 8) ^ ((r & 7) << 3);
    int tok = Ts[r];
    srcA[p] = x_bf + (size_t)tok * H_DIM + koff;
    dstA[p] = &As[(p * 256 + wavebase) * 8];
  }
  const float* Wexp = (e < NEXP) ? (w1 + (size_t)e * (2 * I_DIM) * H_DIM) : sg_w;
  const float* srcB[8];
  float* dstB[8];
#pragma unroll
  for (int p = 0; p < 8; ++p) {
    int c = p * 256 + tid;
    int r = c >> 4;
    int eoff = ((c & 15) ^ (r & 15)) * 4;  // fp32 elems, full 4-bit XOR
    int gr = (r < 64) ? (nt * 64 + r) : (I_DIM + nt * 64 + (r - 64));
    srcB[p] = Wexp + (size_t)gr * H_DIM + eoff;
    dstB[p] = &Bsf[(p * 256 + wavebase) * 4];
  }

  f32x4 acc[4][4];
#pragma unroll
  for (int m = 0; m < 4; ++m)
#pragma unroll
    for (int n = 0; n < 4; ++n) acc[m][n] = (f32x4){0.f, 0.f, 0.f, 0.f};

  int lane = tid & 63, w = tid >> 6, wr = w >> 1, wc = w & 1;
  int laneq = lane & 15, hi = lane >> 4;

  for (int kt = 0; kt < H_DIM / 64; ++kt) {
    if (kt) __syncthreads();
#pragma unroll
    for (int p = 0; p < 4; ++p) gload16(srcA[p] + kt * 64, dstA[p]);
#pragma unroll
    for (int p = 0; p < 8; ++p) gload16(srcB[p] + kt * 64, dstB[p]);
    __syncthreads();
#pragma unroll
    for (int ks = 0; ks < 2; ++ks) {
      bf16x8 a[4], b[4];
#pragma unroll
      for (int f = 0; f < 4; ++f) {
        int rowA = wr * 64 + f * 16 + laneq;
        a[f] = *(const bf16x8*)(As + rowA * 64 + ((ks * 32 + hi * 8) ^ ((rowA & 7) << 3)));
        int rowB = ((f < 2) ? (wc * 32 + f * 16) : (64 + wc * 32 + (f - 2) * 16)) + laneq;
        int s0 = (ks * 8 + hi * 2) ^ (rowB & 15);
        const float* pB = Bsf + rowB * 64;
        b[f] = cvt_frag2(pB + s0 * 4, pB + (s0 ^ 1) * 4);
      }
#pragma unroll
      for (int f = 0; f < 4; ++f)
#pragma unroll
        for (int fn = 0; fn < 4; ++fn)
          acc[f][fn] = __builtin_amdgcn_mfma_f32_16x16x32_bf16(a[f], b[fn], acc[f][fn], 0, 0, 0);
    }
  }

  // epilogue: lane-local silu(g)*u; all 64 lanes store
  const float* bias = (e < NEXP) ? (b1 + (size_t)e * (2 * I_DIM)) : sg_b;
#pragma unroll
  for (int nf = 0; nf < 2; ++nf) {
    int j = nt * 64 + wc * 32 + nf * 16 + laneq;
    float bg = bias[j];
    float bu = bias[I_DIM + j];
#pragma unroll
    for (int mf = 0; mf < 4; ++mf) {
#pragma unroll
      for (int reg = 0; reg < 4; ++reg) {
        int r = wr * 64 + mf * 16 + hi * 4 + reg;
        if (r < n_valid) {
          float g = acc[mf][nf][reg] + bg;
          float u = acc[mf][nf + 2][reg] + bu;
          float s = g / (1.0f + __expf(-g));
          abuf[(size_t)(rbase + rt * 128 + r) * I_DIM + j] = f2b(s * u);
        }
      }
    }
  }
}

// =================================================================
// GEMM2 (R7/R8-verified bf16-B structure): abuf @ W2cat^T * coef.
// 256 thr / 4 waves (2x2), tile 128x128, BK=64, LDS 33KB -> 4 blocks/CU.
// Routed -> packed y rows, shared (e=16) -> out directly. No atomics.
// =================================================================
__global__ __launch_bounds__(256, 4) void gemm2_kernel(
    const u16* __restrict__ abuf, const u16* __restrict__ W2cat,
    const int* __restrict__ tok_of_row, const float* __restrict__ coef_of_row,
    const int* __restrict__ counts,
    float* __restrict__ y, float* __restrict__ out) {
  int nt = blockIdx.x, rt = blockIdx.y, e = blockIdx.z;
  int n_e = (e < NEXP) ? counts[e] : T_TOK;
  if (rt * 128 >= n_e) return;
  int rbase = rowbase_of(counts, e);
  int n_valid = n_e - rt * 128;
  if (n_valid > 128) n_valid = 128;

  __shared__ short As[128 * 64];
  __shared__ short Bs[128 * 64];
  __shared__ int Ts[128];
  __shared__ float Cs[128];

  int tid = threadIdx.x;
  if (tid < 128) {
    bool valid = rt * 128 + tid < n_e;
    int row = rbase + rt * 128 + tid;
    Ts[tid] = valid ? tok_of_row[row] : 0;
    Cs[tid] = valid ? coef_of_row[row] : 0.0f;
  }
  __syncthreads();

  int wavebase = tid & 0xC0;
  const u16* Wb = W2cat + ((e < NEXP)
      ? ((size_t)e * H_DIM + nt * 128) * I_DIM
      : ((size_t)NEXP * H_DIM * I_DIM + (size_t)(nt * 128) * I_DIM));
  const u16* srcA[4];
  short* dstA[4];
  const u16* srcB[4];
  short* dstB[4];
#pragma unroll
  for (int p = 0; p < 4; ++p) {
    int c = p * 256 + tid;
    int r = c >> 3;
    int koff = ((c & 7) * 8) ^ ((r & 7) << 3);
    srcA[p] = abuf + (size_t)(rbase + rt * 128 + r) * I_DIM + koff;
    dstA[p] = &As[(p * 256 + wavebase) * 8];
    srcB[p] = Wb + (size_t)r * I_DIM + koff;
    dstB[p] = &Bs[(p * 256 + wavebase) * 8];
  }

  f32x4 acc[4][4];
#pragma unroll
  for (int m = 0; m < 4; ++m)
#pragma unroll
    for (int n = 0; n < 4; ++n) acc[m][n] = (f32x4){0.f, 0.f, 0.f, 0.f};

  int lane = tid & 63, w = tid >> 6, wr = w >> 1, wc = w & 1;
  int laneq = lane & 15, hi = lane >> 4;

  for (int kt = 0; kt < I_DIM / 64; ++kt) {
    if (kt) __syncthreads();
#pragma unroll
    for (int p = 0; p < 4; ++p) gload16(srcA[p] + kt * 64, dstA[p]);
#pragma unroll
    for (int p = 0; p < 4; ++p) gload16(srcB[p] + kt * 64, dstB[p]);
    __syncthreads();
#pragma unroll
    for (int ks = 0; ks < 2; ++ks) {
      bf16x8 a[4], b[4];
#pragma unroll
      for (int f = 0; f < 4; ++f) {
        int rowA = wr * 64 + f * 16 + laneq;
        int rowB = wc * 64 + f * 16 + laneq;
        a[f] = *(const bf16x8*)(As + rowA * 64 + ((ks * 32 + hi * 8) ^ ((rowA & 7) << 3)));
        b[f] = *(const bf16x8*)(Bs + rowB * 64 + ((ks * 32 + hi * 8) ^ ((rowB & 7) << 3)));
      }
#pragma unroll
      for (int f = 0; f < 4; ++f)
#pragma unroll
        for (int fn = 0; fn < 4; ++fn)
          acc[f][fn] = __builtin_amdgcn_mfma_f32_16x16x32_bf16(a[f], b[fn], acc[f][fn], 0, 0, 0);
    }
  }

#pragma unroll
  for (int mf = 0; mf < 4; ++mf) {
#pragma unroll
    for (int nf = 0; nf < 4; ++nf) {
      int col = nt * 128 + wc * 64 + nf * 16 + laneq;
#pragma unroll
      for (int reg = 0; reg < 4; ++reg) {
        int r = wr * 64 + mf * 16 + hi * 4 + reg;
        if (r < n_valid) {
          float val = acc[mf][nf][reg] * Cs[r];
          if (e < NEXP)
            y[(size_t)(rbase + rt * 128 + r) * H_DIM + col] = val;  // packed row
          else
            out[(size_t)Ts[r] * H_DIM + col] = val;                 // shared covers all
        }
      }
    }
  }
}

// ---------------- combine: out[t] += y[row0(t)] + y[row1(t)] ----------------
__global__ __launch_bounds__(256) void combine_kernel(float* __restrict__ out,
                                                      const float* __restrict__ y,
                                                      const int* __restrict__ row_of_tok) {
  int t = blockIdx.x;
  int r0 = row_of_tok[t * 2];
  int r1 = row_of_tok[t * 2 + 1];
  const float* y0 = y + (size_t)r0 * H_DIM;
  const float* y1 = y + (size_t)r1 * H_DIM;
  float* o = out + (size_t)t * H_DIM;
  int c = threadIdx.x * 8;
#pragma unroll
  for (int h = 0; h < 2; ++h) {
    float4 ov = *(float4*)(o + c + h * 4);
    float4 a = *(const float4*)(y0 + c + h * 4);
    float4 b = *(const float4*)(y1 + c + h * 4);
    ov.x += a.x + b.x; ov.y += a.y + b.y; ov.z += a.z + b.z; ov.w += a.w + b.w;
    *(float4*)(o + c + h * 4) = ov;
  }
}

// ---------------- launch ----------------
extern "C" void kernel_launch(void* const* d_in, const int* in_sizes, int n_in,
                              void* d_out, int out_size, void* d_ws, size_t ws_size,
                              hipStream_t stream) {
  const float* x    = (const float*)d_in[0];
  const float* gate_w = (const float*)d_in[1];
  const float* w1   = (const float*)d_in[2];
  const float* b1   = (const float*)d_in[3];
  const float* w2   = (const float*)d_in[4];
  const float* sg_w = (const float*)d_in[5];
  const float* sg_b = (const float*)d_in[6];
  const float* sd_w = (const float*)d_in[7];
  float* out = (float*)d_out;

  uint8_t* ws = (uint8_t*)d_ws;
  size_t off = 0;
  auto alloc = [&](size_t bytes) -> void* {
    void* p = ws + off;
    off += (bytes + 255) & ~(size_t)255;
    return p;
  };
  u16*  W2cat = (u16*)alloc((size_t)17 * 2048 * 1024 * 2);
  u16*  x_bf  = (u16*)alloc((size_t)T_TOK * H_DIM * 2);
  u16*  abuf  = (u16*)alloc((size_t)NROWS * I_DIM * 2);
  float* y    = (float*)alloc((size_t)NROWS * H_DIM * 4);   // packed routed outputs
  int*  tok_of_row  = (int*)alloc((size_t)NROWS * 4);
  float* coef_of_row = (float*)alloc((size_t)NROWS * 4);
  int*  row_of_tok  = (int*)alloc((size_t)T_TOK * 2 * 4);
  int*  sel   = (int*)alloc((size_t)T_TOK * 2 * 4);
  float* selw = (float*)alloc((size_t)T_TOK * 2 * 4);
  int*  counts  = (int*)alloc(256);
  int*  cursor  = (int*)alloc(256);
  (void)ws_size; (void)in_sizes; (void)n_in; (void)out_size;

  hipMemsetAsync(counts, 0, 512, stream);  // counts + cursor

  router_kernel<<<dim3(T_TOK), dim3(256), 0, stream>>>(x, gate_w, sel, selw, counts, x_bf);
  scatter_kernel<<<dim3(48), dim3(256), 0, stream>>>(sel, selw, counts, cursor,
                                                     tok_of_row, coef_of_row, row_of_tok);

  // x=rt (fastest, shares B-panel), y=nt; z=0: W2 cvt blocks; z=1..17: experts
  gemm1_kernel<<<dim3(32, 16, 18), dim3(256), 0, stream>>>(
      x_bf, w1, sg_w, b1, sg_b, tok_of_row, counts, abuf, w2, sd_w, W2cat);

  gemm2_kernel<<<dim3(16, 32, 17), dim3(256), 0, stream>>>(
      abuf, W2cat, tok_of_row, coef_of_row, counts, y, out);

  combine_kernel<<<dim3(T_TOK), dim3(256), 0, stream>>>(out, y, row_of_tok);
}

// Round 18
// 451.812 us; speedup vs baseline: 2.2678x; 2.2678x over previous
//
#include <hip/hip_runtime.h>
#include <hip/hip_bf16.h>
#include <stdint.h>

#define T_TOK 4096
#define H_DIM 2048
#define I_DIM 1024
#define NEXP  16
#define NROWS 16384

typedef short bf16x8 __attribute__((ext_vector_type(8)));
typedef float f32x4  __attribute__((ext_vector_type(4)));
typedef unsigned short u16;
typedef unsigned short u16x8 __attribute__((ext_vector_type(8)));

__device__ __forceinline__ u16 f2b(float f) {
  union { __hip_bfloat16 h; u16 u; } cv;
  cv.h = __float2bfloat16(f);
  return cv.u;
}

__device__ __forceinline__ void gload16(const void* g, void* l) {
  __builtin_amdgcn_global_load_lds((const __attribute__((address_space(1))) void*)g,
                                   (__attribute__((address_space(3))) void*)l, 16, 0, 0);
}

// 128-aligned prefix base of expert e, recomputed from counts (L2-hot, replaces prefix kernel)
__device__ __forceinline__ int rowbase_of(const int* __restrict__ counts, int e) {
  int acc = 0;
  for (int i = 0; i < e && i < NEXP; ++i) acc += (counts[i] + 127) & ~127;
  return acc;
}

// convert 8 fp32 (two 16B LDS chunks, possibly non-adjacent) -> bf16x8 fragment
__device__ __forceinline__ bf16x8 cvt_frag2(const float* pLo, const float* pHi) {
  f32x4 v0 = *(const f32x4*)pLo;
  f32x4 v1 = *(const f32x4*)pHi;
  bf16x8 o;
  o[0] = (short)f2b(v0[0]); o[1] = (short)f2b(v0[1]);
  o[2] = (short)f2b(v0[2]); o[3] = (short)f2b(v0[3]);
  o[4] = (short)f2b(v1[0]); o[5] = (short)f2b(v1[1]);
  o[6] = (short)f2b(v1[2]); o[7] = (short)f2b(v1[3]);
  return o;
}

// ---------------- router: fp64 logits, top-2, renormalized; also emits x_bf ----------------
__global__ __launch_bounds__(256) void router_kernel(const float* __restrict__ x,
                                                     const float* __restrict__ gw,
                                                     int* __restrict__ sel,
                                                     float* __restrict__ selw,
                                                     int* __restrict__ counts,
                                                     u16* __restrict__ x_bf) {
  int t = blockIdx.x;
  int tid = threadIdx.x;
  const float* xr = x + (size_t)t * H_DIM;
  double p[NEXP];
#pragma unroll
  for (int e = 0; e < NEXP; ++e) p[e] = 0.0;
  bf16x8 xs;
#pragma unroll
  for (int j = 0; j < 8; ++j) {
    int h = tid * 8 + j;
    float xf = xr[h];
    xs[j] = (short)f2b(xf);
    double xv = (double)xf;
#pragma unroll
    for (int e = 0; e < NEXP; ++e) p[e] += xv * (double)gw[e * H_DIM + h];
  }
  *(bf16x8*)(x_bf + (size_t)t * H_DIM + tid * 8) = xs;  // fused x cvt
#pragma unroll
  for (int e = 0; e < NEXP; ++e) {
#pragma unroll
    for (int off = 32; off > 0; off >>= 1) p[e] += __shfl_down(p[e], off);
  }
  __shared__ double sm[4][NEXP];
  int w = tid >> 6;
  if ((tid & 63) == 0) {
#pragma unroll
    for (int e = 0; e < NEXP; ++e) sm[w][e] = p[e];
  }
  __syncthreads();
  if (tid == 0) {
    double l0 = -1e300, l1 = -1e300;
    int e0 = 0, e1 = 0;
    for (int e = 0; e < NEXP; ++e) {
      double v = sm[0][e] + sm[1][e] + sm[2][e] + sm[3][e];
      if (v > l0) { l1 = l0; e1 = e0; l0 = v; e0 = e; }
      else if (v > l1) { l1 = v; e1 = e; }
    }
    double w0 = 1.0 / (1.0 + exp(l1 - l0));
    sel[t * 2 + 0] = e0;
    sel[t * 2 + 1] = e1;
    selw[t * 2 + 0] = (float)w0;
    selw[t * 2 + 1] = (float)(1.0 - w0);
    atomicAdd(&counts[e0], 1);
    atomicAdd(&counts[e1], 1);
  }
}

// ---------------- scatter tokens into packed per-expert row lists ----------------
__global__ __launch_bounds__(256) void scatter_kernel(const int* __restrict__ sel,
                                                      const float* __restrict__ selw,
                                                      const int* __restrict__ counts,
                                                      int* __restrict__ cursor,
                                                      int* __restrict__ tok_of_row,
                                                      float* __restrict__ coef_of_row,
                                                      int* __restrict__ row_of_tok) {
  int idx = blockIdx.x * 256 + threadIdx.x;
  if (idx < T_TOK * 2) {
    int t = idx >> 1;
    int e = sel[idx];
    int slot = atomicAdd(&cursor[e], 1);
    int row = rowbase_of(counts, e) + slot;
    tok_of_row[row] = t;
    coef_of_row[row] = selw[idx];
    row_of_tok[idx] = row;
  } else if (idx < T_TOK * 3) {
    int t = idx - T_TOK * 2;
    int sb = rowbase_of(counts, NEXP);
    tok_of_row[sb + t] = t;
    coef_of_row[sb + t] = 1.0f;
  }
}

// =================================================================
// GEMM1 (R16-verified grid: nt fastest -> A-tile L2 reuse across 16 blocks).
// fp32-B-direct m97 structure + fused W2 cvt at z=0.
// 256 thr / 4 waves (2x2), tile 128x128, BK=64, LDS ~49KB -> 3 blocks/CU.
// A swizzle (0 conflicts): chunk c(8 bf16) -> row=c>>3,
//   koff=((c&7)*8)^((r&7)<<3); read (ks*32+hi*8)^((row&7)<<3).
// B fp32 swizzle (0 conflicts): chunk c(4 f32) -> row=c>>4,
//   src elem off=((c&15)^(r&15))*4; read slots s0=(ks*8+hi*2)^(r&15), s0^1.
// =================================================================
__global__ __launch_bounds__(256, 3) void gemm1_kernel(
    const u16* __restrict__ x_bf, const float* __restrict__ w1,
    const float* __restrict__ sg_w,
    const float* __restrict__ b1, const float* __restrict__ sg_b,
    const int* __restrict__ tok_of_row, const int* __restrict__ counts,
    u16* __restrict__ abuf,
    const float* __restrict__ w2, const float* __restrict__ sd_w,
    u16* __restrict__ W2cat) {
  int tid = threadIdx.x;

  if (blockIdx.z == 0) {
    // ---- W2/sd_w fp32 -> bf16 cvt, grid-stride over 512 blocks ----
    const int N2 = 16 * 2048 * 1024 / 8;  // w2 in 8-float units
    const int N3 = 2048 * 1024 / 8;       // sd_w
    int lin = blockIdx.y * 16 + blockIdx.x;          // [0,512)
    int gid = lin * 256 + tid;
    int stride = 512 * 256;
    u16x8* dst = (u16x8*)W2cat;
    for (int i = gid; i < N2 + N3; i += stride) {
      const float4* s = (i < N2) ? ((const float4*)w2 + 2 * (size_t)i)
                                 : ((const float4*)sd_w + 2 * (size_t)(i - N2));
      float4 v0 = s[0];
      float4 v1 = s[1];
      u16x8 o;
      o[0] = f2b(v0.x); o[1] = f2b(v0.y); o[2] = f2b(v0.z); o[3] = f2b(v0.w);
      o[4] = f2b(v1.x); o[5] = f2b(v1.y); o[6] = f2b(v1.z); o[7] = f2b(v1.w);
      dst[i] = o;
    }
    return;
  }

  int nt = blockIdx.x, rt = blockIdx.y, e = blockIdx.z - 1;
  int n_e = (e < NEXP) ? counts[e] : T_TOK;
  if (rt * 128 >= n_e) return;
  int rbase = rowbase_of(counts, e);
  int n_valid = n_e - rt * 128;
  if (n_valid > 128) n_valid = 128;

  __shared__ short As[128 * 64];   // bf16, swizzled
  __shared__ float Bsf[128 * 64];  // fp32, swizzled
  __shared__ int Ts[128];

  if (tid < 128)
    Ts[tid] = (rt * 128 + tid < n_e) ? tok_of_row[rbase + rt * 128 + tid] : 0;
  __syncthreads();

  int wavebase = tid & 0xC0;
  const u16* srcA[4];
  short* dstA[4];
#pragma unroll
  for (int p = 0; p < 4; ++p) {
    int c = p * 256 + tid;
    int r = c >> 3;
    int koff = ((c & 7) * 8) ^ ((r & 7) << 3);
    int tok = Ts[r];
    srcA[p] = x_bf + (size_t)tok * H_DIM + koff;
    dstA[p] = &As[(p * 256 + wavebase) * 8];
  }
  const float* Wexp = (e < NEXP) ? (w1 + (size_t)e * (2 * I_DIM) * H_DIM) : sg_w;
  const float* srcB[8];
  float* dstB[8];
#pragma unroll
  for (int p = 0; p < 8; ++p) {
    int c = p * 256 + tid;
    int r = c >> 4;
    int eoff = ((c & 15) ^ (r & 15)) * 4;  // fp32 elems, full 4-bit XOR
    int gr = (r < 64) ? (nt * 64 + r) : (I_DIM + nt * 64 + (r - 64));
    srcB[p] = Wexp + (size_t)gr * H_DIM + eoff;
    dstB[p] = &Bsf[(p * 256 + wavebase) * 4];
  }

  f32x4 acc[4][4];
#pragma unroll
  for (int m = 0; m < 4; ++m)
#pragma unroll
    for (int n = 0; n < 4; ++n) acc[m][n] = (f32x4){0.f, 0.f, 0.f, 0.f};

  int lane = tid & 63, w = tid >> 6, wr = w >> 1, wc = w & 1;
  int laneq = lane & 15, hi = lane >> 4;

  for (int kt = 0; kt < H_DIM / 64; ++kt) {
    if (kt) __syncthreads();
#pragma unroll
    for (int p = 0; p < 4; ++p) gload16(srcA[p] + kt * 64, dstA[p]);
#pragma unroll
    for (int p = 0; p < 8; ++p) gload16(srcB[p] + kt * 64, dstB[p]);
    __syncthreads();
#pragma unroll
    for (int ks = 0; ks < 2; ++ks) {
      bf16x8 a[4], b[4];
#pragma unroll
      for (int f = 0; f < 4; ++f) {
        int rowA = wr * 64 + f * 16 + laneq;
        a[f] = *(const bf16x8*)(As + rowA * 64 + ((ks * 32 + hi * 8) ^ ((rowA & 7) << 3)));
        int rowB = ((f < 2) ? (wc * 32 + f * 16) : (64 + wc * 32 + (f - 2) * 16)) + laneq;
        int s0 = (ks * 8 + hi * 2) ^ (rowB & 15);
        const float* pB = Bsf + rowB * 64;
        b[f] = cvt_frag2(pB + s0 * 4, pB + (s0 ^ 1) * 4);
      }
#pragma unroll
      for (int f = 0; f < 4; ++f)
#pragma unroll
        for (int fn = 0; fn < 4; ++fn)
          acc[f][fn] = __builtin_amdgcn_mfma_f32_16x16x32_bf16(a[f], b[fn], acc[f][fn], 0, 0, 0);
    }
  }

  // epilogue: lane-local silu(g)*u; all 64 lanes store
  const float* bias = (e < NEXP) ? (b1 + (size_t)e * (2 * I_DIM)) : sg_b;
#pragma unroll
  for (int nf = 0; nf < 2; ++nf) {
    int j = nt * 64 + wc * 32 + nf * 16 + laneq;
    float bg = bias[j];
    float bu = bias[I_DIM + j];
#pragma unroll
    for (int mf = 0; mf < 4; ++mf) {
#pragma unroll
      for (int reg = 0; reg < 4; ++reg) {
        int r = wr * 64 + mf * 16 + hi * 4 + reg;
        if (r < n_valid) {
          float g = acc[mf][nf][reg] + bg;
          float u = acc[mf][nf + 2][reg] + bu;
          float s = g / (1.0f + __expf(-g));
          abuf[(size_t)(rbase + rt * 128 + r) * I_DIM + j] = f2b(s * u);
        }
      }
    }
  }
}

// =================================================================
// GEMM2 (R7/R8-verified bf16-B structure): abuf @ W2cat^T * coef.
// 256 thr / 4 waves (2x2), tile 128x128, BK=64, LDS 33KB -> 4 blocks/CU.
// Routed -> packed y rows, shared (e=16) -> out directly. No atomics.
// =================================================================
__global__ __launch_bounds__(256, 4) void gemm2_kernel(
    const u16* __restrict__ abuf, const u16* __restrict__ W2cat,
    const int* __restrict__ tok_of_row, const float* __restrict__ coef_of_row,
    const int* __restrict__ counts,
    float* __restrict__ y, float* __restrict__ out) {
  int nt = blockIdx.x, rt = blockIdx.y, e = blockIdx.z;
  int n_e = (e < NEXP) ? counts[e] : T_TOK;
  if (rt * 128 >= n_e) return;
  int rbase = rowbase_of(counts, e);
  int n_valid = n_e - rt * 128;
  if (n_valid > 128) n_valid = 128;

  __shared__ short As[128 * 64];
  __shared__ short Bs[128 * 64];
  __shared__ int Ts[128];
  __shared__ float Cs[128];

  int tid = threadIdx.x;
  if (tid < 128) {
    bool valid = rt * 128 + tid < n_e;
    int row = rbase + rt * 128 + tid;
    Ts[tid] = valid ? tok_of_row[row] : 0;
    Cs[tid] = valid ? coef_of_row[row] : 0.0f;
  }
  __syncthreads();

  int wavebase = tid & 0xC0;
  const u16* Wb = W2cat + ((e < NEXP)
      ? ((size_t)e * H_DIM + nt * 128) * I_DIM
      : ((size_t)NEXP * H_DIM * I_DIM + (size_t)(nt * 128) * I_DIM));
  const u16* srcA[4];
  short* dstA[4];
  const u16* srcB[4];
  short* dstB[4];
#pragma unroll
  for (int p = 0; p < 4; ++p) {
    int c = p * 256 + tid;
    int r = c >> 3;
    int koff = ((c & 7) * 8) ^ ((r & 7) << 3);
    srcA[p] = abuf + (size_t)(rbase + rt * 128 + r) * I_DIM + koff;
    dstA[p] = &As[(p * 256 + wavebase) * 8];
    srcB[p] = Wb + (size_t)r * I_DIM + koff;
    dstB[p] = &Bs[(p * 256 + wavebase) * 8];
  }

  f32x4 acc[4][4];
#pragma unroll
  for (int m = 0; m < 4; ++m)
#pragma unroll
    for (int n = 0; n < 4; ++n) acc[m][n] = (f32x4){0.f, 0.f, 0.f, 0.f};

  int lane = tid & 63, w = tid >> 6, wr = w >> 1, wc = w & 1;
  int laneq = lane & 15, hi = lane >> 4;

  for (int kt = 0; kt < I_DIM / 64; ++kt) {
    if (kt) __syncthreads();
#pragma unroll
    for (int p = 0; p < 4; ++p) gload16(srcA[p] + kt * 64, dstA[p]);
#pragma unroll
    for (int p = 0; p < 4; ++p) gload16(srcB[p] + kt * 64, dstB[p]);
    __syncthreads();
#pragma unroll
    for (int ks = 0; ks < 2; ++ks) {
      bf16x8 a[4], b[4];
#pragma unroll
      for (int f = 0; f < 4; ++f) {
        int rowA = wr * 64 + f * 16 + laneq;
        int rowB = wc * 64 + f * 16 + laneq;
        a[f] = *(const bf16x8*)(As + rowA * 64 + ((ks * 32 + hi * 8) ^ ((rowA & 7) << 3)));
        b[f] = *(const bf16x8*)(Bs + rowB * 64 + ((ks * 32 + hi * 8) ^ ((rowB & 7) << 3)));
      }
#pragma unroll
      for (int f = 0; f < 4; ++f)
#pragma unroll
        for (int fn = 0; fn < 4; ++fn)
          acc[f][fn] = __builtin_amdgcn_mfma_f32_16x16x32_bf16(a[f], b[fn], acc[f][fn], 0, 0, 0);
    }
  }

#pragma unroll
  for (int mf = 0; mf < 4; ++mf) {
#pragma unroll
    for (int nf = 0; nf < 4; ++nf) {
      int col = nt * 128 + wc * 64 + nf * 16 + laneq;
#pragma unroll
      for (int reg = 0; reg < 4; ++reg) {
        int r = wr * 64 + mf * 16 + hi * 4 + reg;
        if (r < n_valid) {
          float val = acc[mf][nf][reg] * Cs[r];
          if (e < NEXP)
            y[(size_t)(rbase + rt * 128 + r) * H_DIM + col] = val;  // packed row
          else
            out[(size_t)Ts[r] * H_DIM + col] = val;                 // shared covers all
        }
      }
    }
  }
}

// ---------------- combine: out[t] += y[row0(t)] + y[row1(t)] ----------------
__global__ __launch_bounds__(256) void combine_kernel(float* __restrict__ out,
                                                      const float* __restrict__ y,
                                                      const int* __restrict__ row_of_tok) {
  int t = blockIdx.x;
  int r0 = row_of_tok[t * 2];
  int r1 = row_of_tok[t * 2 + 1];
  const float* y0 = y + (size_t)r0 * H_DIM;
  const float* y1 = y + (size_t)r1 * H_DIM;
  float* o = out + (size_t)t * H_DIM;
  int c = threadIdx.x * 8;
#pragma unroll
  for (int h = 0; h < 2; ++h) {
    float4 ov = *(float4*)(o + c + h * 4);
    float4 a = *(const float4*)(y0 + c + h * 4);
    float4 b = *(const float4*)(y1 + c + h * 4);
    ov.x += a.x + b.x; ov.y += a.y + b.y; ov.z += a.z + b.z; ov.w += a.w + b.w;
    *(float4*)(o + c + h * 4) = ov;
  }
}

// ---------------- launch ----------------
extern "C" void kernel_launch(void* const* d_in, const int* in_sizes, int n_in,
                              void* d_out, int out_size, void* d_ws, size_t ws_size,
                              hipStream_t stream) {
  const float* x    = (const float*)d_in[0];
  const float* gate_w = (const float*)d_in[1];
  const float* w1   = (const float*)d_in[2];
  const float* b1   = (const float*)d_in[3];
  const float* w2   = (const float*)d_in[4];
  const float* sg_w = (const float*)d_in[5];
  const float* sg_b = (const float*)d_in[6];
  const float* sd_w = (const float*)d_in[7];
  float* out = (float*)d_out;

  uint8_t* ws = (uint8_t*)d_ws;
  size_t off = 0;
  auto alloc = [&](size_t bytes) -> void* {
    void* p = ws + off;
    off += (bytes + 255) & ~(size_t)255;
    return p;
  };
  u16*  W2cat = (u16*)alloc((size_t)17 * 2048 * 1024 * 2);
  u16*  x_bf  = (u16*)alloc((size_t)T_TOK * H_DIM * 2);
  u16*  abuf  = (u16*)alloc((size_t)NROWS * I_DIM * 2);
  float* y    = (float*)alloc((size_t)NROWS * H_DIM * 4);   // packed routed outputs
  int*  tok_of_row  = (int*)alloc((size_t)NROWS * 4);
  float* coef_of_row = (float*)alloc((size_t)NROWS * 4);
  int*  row_of_tok  = (int*)alloc((size_t)T_TOK * 2 * 4);
  int*  sel   = (int*)alloc((size_t)T_TOK * 2 * 4);
  float* selw = (float*)alloc((size_t)T_TOK * 2 * 4);
  int*  counts  = (int*)alloc(256);
  int*  cursor  = (int*)alloc(256);
  (void)ws_size; (void)in_sizes; (void)n_in; (void)out_size;

  hipMemsetAsync(counts, 0, 512, stream);  // counts + cursor

  router_kernel<<<dim3(T_TOK), dim3(256), 0, stream>>>(x, gate_w, sel, selw, counts, x_bf);
  scatter_kernel<<<dim3(48), dim3(256), 0, stream>>>(sel, selw, counts, cursor,
                                                     tok_of_row, coef_of_row, row_of_tok);

  // R16 grid: x=nt (fastest, shares gathered A-tile across 16 blocks), y=rt;
  // z=0: W2 cvt blocks (overlap gemm1's idle BW); z=1..17: experts
  gemm1_kernel<<<dim3(16, 32, 18), dim3(256), 0, stream>>>(
      x_bf, w1, sg_w, b1, sg_b, tok_of_row, counts, abuf, w2, sd_w, W2cat);

  gemm2_kernel<<<dim3(16, 32, 17), dim3(256), 0, stream>>>(
      abuf, W2cat, tok_of_row, coef_of_row, counts, y, out);

  combine_kernel<<<dim3(T_TOK), dim3(256), 0, stream>>>(out, y, row_of_tok);
}

// Round 19
// 446.305 us; speedup vs baseline: 2.2958x; 1.0123x over previous
//
#include <hip/hip_runtime.h>
#include <hip/hip_bf16.h>
#include <stdint.h>

#define T_TOK 4096
#define H_DIM 2048
#define I_DIM 1024
#define NEXP  16
#define NROWS 16384

typedef short bf16x8 __attribute__((ext_vector_type(8)));
typedef float f32x4  __attribute__((ext_vector_type(4)));
typedef unsigned short u16;
typedef unsigned short u16x8 __attribute__((ext_vector_type(8)));

__device__ __forceinline__ u16 f2b(float f) {
  union { __hip_bfloat16 h; u16 u; } cv;
  cv.h = __float2bfloat16(f);
  return cv.u;
}

__device__ __forceinline__ float b2f(u16 u) {
  union { unsigned int i; float f; } cv;
  cv.i = ((unsigned int)u) << 16;
  return cv.f;
}

__device__ __forceinline__ void gload16(const void* g, void* l) {
  __builtin_amdgcn_global_load_lds((const __attribute__((address_space(1))) void*)g,
                                   (__attribute__((address_space(3))) void*)l, 16, 0, 0);
}

// 128-aligned prefix base of expert e, recomputed from counts (L2-hot, replaces prefix kernel)
__device__ __forceinline__ int rowbase_of(const int* __restrict__ counts, int e) {
  int acc = 0;
  for (int i = 0; i < e && i < NEXP; ++i) acc += (counts[i] + 127) & ~127;
  return acc;
}

// convert 8 fp32 (two 16B LDS chunks, possibly non-adjacent) -> bf16x8 fragment
__device__ __forceinline__ bf16x8 cvt_frag2(const float* pLo, const float* pHi) {
  f32x4 v0 = *(const f32x4*)pLo;
  f32x4 v1 = *(const f32x4*)pHi;
  bf16x8 o;
  o[0] = (short)f2b(v0[0]); o[1] = (short)f2b(v0[1]);
  o[2] = (short)f2b(v0[2]); o[3] = (short)f2b(v0[3]);
  o[4] = (short)f2b(v1[0]); o[5] = (short)f2b(v1[1]);
  o[6] = (short)f2b(v1[2]); o[7] = (short)f2b(v1[3]);
  return o;
}

// ---------------- router: fp64 logits, top-2, renormalized; also emits x_bf ----------------
__global__ __launch_bounds__(256) void router_kernel(const float* __restrict__ x,
                                                     const float* __restrict__ gw,
                                                     int* __restrict__ sel,
                                                     float* __restrict__ selw,
                                                     int* __restrict__ counts,
                                                     u16* __restrict__ x_bf) {
  int t = blockIdx.x;
  int tid = threadIdx.x;
  const float* xr = x + (size_t)t * H_DIM;
  double p[NEXP];
#pragma unroll
  for (int e = 0; e < NEXP; ++e) p[e] = 0.0;
  bf16x8 xs;
#pragma unroll
  for (int j = 0; j < 8; ++j) {
    int h = tid * 8 + j;
    float xf = xr[h];
    xs[j] = (short)f2b(xf);
    double xv = (double)xf;
#pragma unroll
    for (int e = 0; e < NEXP; ++e) p[e] += xv * (double)gw[e * H_DIM + h];
  }
  *(bf16x8*)(x_bf + (size_t)t * H_DIM + tid * 8) = xs;  // fused x cvt
#pragma unroll
  for (int e = 0; e < NEXP; ++e) {
#pragma unroll
    for (int off = 32; off > 0; off >>= 1) p[e] += __shfl_down(p[e], off);
  }
  __shared__ double sm[4][NEXP];
  int w = tid >> 6;
  if ((tid & 63) == 0) {
#pragma unroll
    for (int e = 0; e < NEXP; ++e) sm[w][e] = p[e];
  }
  __syncthreads();
  if (tid == 0) {
    double l0 = -1e300, l1 = -1e300;
    int e0 = 0, e1 = 0;
    for (int e = 0; e < NEXP; ++e) {
      double v = sm[0][e] + sm[1][e] + sm[2][e] + sm[3][e];
      if (v > l0) { l1 = l0; e1 = e0; l0 = v; e0 = e; }
      else if (v > l1) { l1 = v; e1 = e; }
    }
    double w0 = 1.0 / (1.0 + exp(l1 - l0));
    sel[t * 2 + 0] = e0;
    sel[t * 2 + 1] = e1;
    selw[t * 2 + 0] = (float)w0;
    selw[t * 2 + 1] = (float)(1.0 - w0);
    atomicAdd(&counts[e0], 1);
    atomicAdd(&counts[e1], 1);
  }
}

// ---------------- scatter tokens into packed per-expert row lists ----------------
__global__ __launch_bounds__(256) void scatter_kernel(const int* __restrict__ sel,
                                                      const float* __restrict__ selw,
                                                      const int* __restrict__ counts,
                                                      int* __restrict__ cursor,
                                                      int* __restrict__ tok_of_row,
                                                      float* __restrict__ coef_of_row,
                                                      int* __restrict__ row_of_tok) {
  int idx = blockIdx.x * 256 + threadIdx.x;
  if (idx < T_TOK * 2) {
    int t = idx >> 1;
    int e = sel[idx];
    int slot = atomicAdd(&cursor[e], 1);
    int row = rowbase_of(counts, e) + slot;
    tok_of_row[row] = t;
    coef_of_row[row] = selw[idx];
    row_of_tok[idx] = row;
  } else if (idx < T_TOK * 3) {
    int t = idx - T_TOK * 2;
    int sb = rowbase_of(counts, NEXP);
    tok_of_row[sb + t] = t;
    coef_of_row[sb + t] = 1.0f;
  }
}

// =================================================================
// GEMM1 (R16-verified grid: nt fastest -> A-tile L2 reuse across 16 blocks).
// fp32-B-direct m97 structure + fused W2 cvt at z=0.
// 256 thr / 4 waves (2x2), tile 128x128, BK=64, LDS ~49KB -> 3 blocks/CU.
// A swizzle (0 conflicts): chunk c(8 bf16) -> row=c>>3,
//   koff=((c&7)*8)^((r&7)<<3); read (ks*32+hi*8)^((row&7)<<3).
// B fp32 swizzle (0 conflicts): chunk c(4 f32) -> row=c>>4,
//   src elem off=((c&15)^(r&15))*4; read slots s0=(ks*8+hi*2)^(r&15), s0^1.
// =================================================================
__global__ __launch_bounds__(256, 3) void gemm1_kernel(
    const u16* __restrict__ x_bf, const float* __restrict__ w1,
    const float* __restrict__ sg_w,
    const float* __restrict__ b1, const float* __restrict__ sg_b,
    const int* __restrict__ tok_of_row, const int* __restrict__ counts,
    u16* __restrict__ abuf,
    const float* __restrict__ w2, const float* __restrict__ sd_w,
    u16* __restrict__ W2cat) {
  int tid = threadIdx.x;

  if (blockIdx.z == 0) {
    // ---- W2/sd_w fp32 -> bf16 cvt, grid-stride over 512 blocks ----
    const int N2 = 16 * 2048 * 1024 / 8;  // w2 in 8-float units
    const int N3 = 2048 * 1024 / 8;       // sd_w
    int lin = blockIdx.y * 16 + blockIdx.x;          // [0,512)
    int gid = lin * 256 + tid;
    int stride = 512 * 256;
    u16x8* dst = (u16x8*)W2cat;
    for (int i = gid; i < N2 + N3; i += stride) {
      const float4* s = (i < N2) ? ((const float4*)w2 + 2 * (size_t)i)
                                 : ((const float4*)sd_w + 2 * (size_t)(i - N2));
      float4 v0 = s[0];
      float4 v1 = s[1];
      u16x8 o;
      o[0] = f2b(v0.x); o[1] = f2b(v0.y); o[2] = f2b(v0.z); o[3] = f2b(v0.w);
      o[4] = f2b(v1.x); o[5] = f2b(v1.y); o[6] = f2b(v1.z); o[7] = f2b(v1.w);
      dst[i] = o;
    }
    return;
  }

  int nt = blockIdx.x, rt = blockIdx.y, e = blockIdx.z - 1;
  int n_e = (e < NEXP) ? counts[e] : T_TOK;
  if (rt * 128 >= n_e) return;
  int rbase = rowbase_of(counts, e);
  int n_valid = n_e - rt * 128;
  if (n_valid > 128) n_valid = 128;

  __shared__ short As[128 * 64];   // bf16, swizzled
  __shared__ float Bsf[128 * 64];  // fp32, swizzled
  __shared__ int Ts[128];

  if (tid < 128)
    Ts[tid] = (rt * 128 + tid < n_e) ? tok_of_row[rbase + rt * 128 + tid] : 0;
  __syncthreads();

  int wavebase = tid & 0xC0;
  const u16* srcA[4];
  short* dstA[4];
#pragma unroll
  for (int p = 0; p < 4; ++p) {
    int c = p * 256 + tid;
    int r = c >> 3;
    int koff = ((c & 7) * 8) ^ ((r & 7) << 3);
    int tok = Ts[r];
    srcA[p] = x_bf + (size_t)tok * H_DIM + koff;
    dstA[p] = &As[(p * 256 + wavebase) * 8];
  }
  const float* Wexp = (e < NEXP) ? (w1 + (size_t)e * (2 * I_DIM) * H_DIM) : sg_w;
  const float* srcB[8];
  float* dstB[8];
#pragma unroll
  for (int p = 0; p < 8; ++p) {
    int c = p * 256 + tid;
    int r = c >> 4;
    int eoff = ((c & 15) ^ (r & 15)) * 4;  // fp32 elems, full 4-bit XOR
    int gr = (r < 64) ? (nt * 64 + r) : (I_DIM + nt * 64 + (r - 64));
    srcB[p] = Wexp + (size_t)gr * H_DIM + eoff;
    dstB[p] = &Bsf[(p * 256 + wavebase) * 4];
  }

  f32x4 acc[4][4];
#pragma unroll
  for (int m = 0; m < 4; ++m)
#pragma unroll
    for (int n = 0; n < 4; ++n) acc[m][n] = (f32x4){0.f, 0.f, 0.f, 0.f};

  int lane = tid & 63, w = tid >> 6, wr = w >> 1, wc = w & 1;
  int laneq = lane & 15, hi = lane >> 4;

  for (int kt = 0; kt < H_DIM / 64; ++kt) {
    if (kt) __syncthreads();
#pragma unroll
    for (int p = 0; p < 4; ++p) gload16(srcA[p] + kt * 64, dstA[p]);
#pragma unroll
    for (int p = 0; p < 8; ++p) gload16(srcB[p] + kt * 64, dstB[p]);
    __syncthreads();
#pragma unroll
    for (int ks = 0; ks < 2; ++ks) {
      bf16x8 a[4], b[4];
#pragma unroll
      for (int f = 0; f < 4; ++f) {
        int rowA = wr * 64 + f * 16 + laneq;
        a[f] = *(const bf16x8*)(As + rowA * 64 + ((ks * 32 + hi * 8) ^ ((rowA & 7) << 3)));
        int rowB = ((f < 2) ? (wc * 32 + f * 16) : (64 + wc * 32 + (f - 2) * 16)) + laneq;
        int s0 = (ks * 8 + hi * 2) ^ (rowB & 15);
        const float* pB = Bsf + rowB * 64;
        b[f] = cvt_frag2(pB + s0 * 4, pB + (s0 ^ 1) * 4);
      }
#pragma unroll
      for (int f = 0; f < 4; ++f)
#pragma unroll
        for (int fn = 0; fn < 4; ++fn)
          acc[f][fn] = __builtin_amdgcn_mfma_f32_16x16x32_bf16(a[f], b[fn], acc[f][fn], 0, 0, 0);
    }
  }

  // epilogue: lane-local silu(g)*u; all 64 lanes store
  const float* bias = (e < NEXP) ? (b1 + (size_t)e * (2 * I_DIM)) : sg_b;
#pragma unroll
  for (int nf = 0; nf < 2; ++nf) {
    int j = nt * 64 + wc * 32 + nf * 16 + laneq;
    float bg = bias[j];
    float bu = bias[I_DIM + j];
#pragma unroll
    for (int mf = 0; mf < 4; ++mf) {
#pragma unroll
      for (int reg = 0; reg < 4; ++reg) {
        int r = wr * 64 + mf * 16 + hi * 4 + reg;
        if (r < n_valid) {
          float g = acc[mf][nf][reg] + bg;
          float u = acc[mf][nf + 2][reg] + bu;
          float s = g / (1.0f + __expf(-g));
          abuf[(size_t)(rbase + rt * 128 + r) * I_DIM + j] = f2b(s * u);
        }
      }
    }
  }
}

// =================================================================
// GEMM2 (R7/R8-verified bf16-B structure): abuf @ W2cat^T * coef.
// 256 thr / 4 waves (2x2), tile 128x128, BK=64, LDS 33KB -> 4 blocks/CU.
// Routed -> packed y rows (bf16, halves y traffic), shared (e=16) -> out
// directly. No atomics.
// =================================================================
__global__ __launch_bounds__(256, 4) void gemm2_kernel(
    const u16* __restrict__ abuf, const u16* __restrict__ W2cat,
    const int* __restrict__ tok_of_row, const float* __restrict__ coef_of_row,
    const int* __restrict__ counts,
    u16* __restrict__ y, float* __restrict__ out) {
  int nt = blockIdx.x, rt = blockIdx.y, e = blockIdx.z;
  int n_e = (e < NEXP) ? counts[e] : T_TOK;
  if (rt * 128 >= n_e) return;
  int rbase = rowbase_of(counts, e);
  int n_valid = n_e - rt * 128;
  if (n_valid > 128) n_valid = 128;

  __shared__ short As[128 * 64];
  __shared__ short Bs[128 * 64];
  __shared__ int Ts[128];
  __shared__ float Cs[128];

  int tid = threadIdx.x;
  if (tid < 128) {
    bool valid = rt * 128 + tid < n_e;
    int row = rbase + rt * 128 + tid;
    Ts[tid] = valid ? tok_of_row[row] : 0;
    Cs[tid] = valid ? coef_of_row[row] : 0.0f;
  }
  __syncthreads();

  int wavebase = tid & 0xC0;
  const u16* Wb = W2cat + ((e < NEXP)
      ? ((size_t)e * H_DIM + nt * 128) * I_DIM
      : ((size_t)NEXP * H_DIM * I_DIM + (size_t)(nt * 128) * I_DIM));
  const u16* srcA[4];
  short* dstA[4];
  const u16* srcB[4];
  short* dstB[4];
#pragma unroll
  for (int p = 0; p < 4; ++p) {
    int c = p * 256 + tid;
    int r = c >> 3;
    int koff = ((c & 7) * 8) ^ ((r & 7) << 3);
    srcA[p] = abuf + (size_t)(rbase + rt * 128 + r) * I_DIM + koff;
    dstA[p] = &As[(p * 256 + wavebase) * 8];
    srcB[p] = Wb + (size_t)r * I_DIM + koff;
    dstB[p] = &Bs[(p * 256 + wavebase) * 8];
  }

  f32x4 acc[4][4];
#pragma unroll
  for (int m = 0; m < 4; ++m)
#pragma unroll
    for (int n = 0; n < 4; ++n) acc[m][n] = (f32x4){0.f, 0.f, 0.f, 0.f};

  int lane = tid & 63, w = tid >> 6, wr = w >> 1, wc = w & 1;
  int laneq = lane & 15, hi = lane >> 4;

  for (int kt = 0; kt < I_DIM / 64; ++kt) {
    if (kt) __syncthreads();
#pragma unroll
    for (int p = 0; p < 4; ++p) gload16(srcA[p] + kt * 64, dstA[p]);
#pragma unroll
    for (int p = 0; p < 4; ++p) gload16(srcB[p] + kt * 64, dstB[p]);
    __syncthreads();
#pragma unroll
    for (int ks = 0; ks < 2; ++ks) {
      bf16x8 a[4], b[4];
#pragma unroll
      for (int f = 0; f < 4; ++f) {
        int rowA = wr * 64 + f * 16 + laneq;
        int rowB = wc * 64 + f * 16 + laneq;
        a[f] = *(const bf16x8*)(As + rowA * 64 + ((ks * 32 + hi * 8) ^ ((rowA & 7) << 3)));
        b[f] = *(const bf16x8*)(Bs + rowB * 64 + ((ks * 32 + hi * 8) ^ ((rowB & 7) << 3)));
      }
#pragma unroll
      for (int f = 0; f < 4; ++f)
#pragma unroll
        for (int fn = 0; fn < 4; ++fn)
          acc[f][fn] = __builtin_amdgcn_mfma_f32_16x16x32_bf16(a[f], b[fn], acc[f][fn], 0, 0, 0);
    }
  }

#pragma unroll
  for (int mf = 0; mf < 4; ++mf) {
#pragma unroll
    for (int nf = 0; nf < 4; ++nf) {
      int col = nt * 128 + wc * 64 + nf * 16 + laneq;
#pragma unroll
      for (int reg = 0; reg < 4; ++reg) {
        int r = wr * 64 + mf * 16 + hi * 4 + reg;
        if (r < n_valid) {
          float val = acc[mf][nf][reg] * Cs[r];
          if (e < NEXP)
            y[(size_t)(rbase + rt * 128 + r) * H_DIM + col] = f2b(val);  // bf16 packed row
          else
            out[(size_t)Ts[r] * H_DIM + col] = val;                      // shared covers all
        }
      }
    }
  }
}

// ---------------- combine: out[t] += y[row0(t)] + y[row1(t)]  (y is bf16) ----------------
__global__ __launch_bounds__(256) void combine_kernel(float* __restrict__ out,
                                                      const u16* __restrict__ y,
                                                      const int* __restrict__ row_of_tok) {
  int t = blockIdx.x;
  int r0 = row_of_tok[t * 2];
  int r1 = row_of_tok[t * 2 + 1];
  const u16* y0 = y + (size_t)r0 * H_DIM;
  const u16* y1 = y + (size_t)r1 * H_DIM;
  float* o = out + (size_t)t * H_DIM;
  int c = threadIdx.x * 8;
  u16x8 a8 = *(const u16x8*)(y0 + c);
  u16x8 b8 = *(const u16x8*)(y1 + c);
#pragma unroll
  for (int h = 0; h < 2; ++h) {
    float4 ov = *(float4*)(o + c + h * 4);
    ov.x += b2f(a8[h * 4 + 0]) + b2f(b8[h * 4 + 0]);
    ov.y += b2f(a8[h * 4 + 1]) + b2f(b8[h * 4 + 1]);
    ov.z += b2f(a8[h * 4 + 2]) + b2f(b8[h * 4 + 2]);
    ov.w += b2f(a8[h * 4 + 3]) + b2f(b8[h * 4 + 3]);
    *(float4*)(o + c + h * 4) = ov;
  }
}

// ---------------- launch ----------------
extern "C" void kernel_launch(void* const* d_in, const int* in_sizes, int n_in,
                              void* d_out, int out_size, void* d_ws, size_t ws_size,
                              hipStream_t stream) {
  const float* x    = (const float*)d_in[0];
  const float* gate_w = (const float*)d_in[1];
  const float* w1   = (const float*)d_in[2];
  const float* b1   = (const float*)d_in[3];
  const float* w2   = (const float*)d_in[4];
  const float* sg_w = (const float*)d_in[5];
  const float* sg_b = (const float*)d_in[6];
  const float* sd_w = (const float*)d_in[7];
  float* out = (float*)d_out;

  uint8_t* ws = (uint8_t*)d_ws;
  size_t off = 0;
  auto alloc = [&](size_t bytes) -> void* {
    void* p = ws + off;
    off += (bytes + 255) & ~(size_t)255;
    return p;
  };
  u16*  W2cat = (u16*)alloc((size_t)17 * 2048 * 1024 * 2);
  u16*  x_bf  = (u16*)alloc((size_t)T_TOK * H_DIM * 2);
  u16*  abuf  = (u16*)alloc((size_t)NROWS * I_DIM * 2);
  u16*  y     = (u16*)alloc((size_t)NROWS * H_DIM * 2);   // packed routed outputs (bf16)
  int*  tok_of_row  = (int*)alloc((size_t)NROWS * 4);
  float* coef_of_row = (float*)alloc((size_t)NROWS * 4);
  int*  row_of_tok  = (int*)alloc((size_t)T_TOK * 2 * 4);
  int*  sel   = (int*)alloc((size_t)T_TOK * 2 * 4);
  float* selw = (float*)alloc((size_t)T_TOK * 2 * 4);
  int*  counts  = (int*)alloc(256);
  int*  cursor  = (int*)alloc(256);
  (void)ws_size; (void)in_sizes; (void)n_in; (void)out_size;

  hipMemsetAsync(counts, 0, 512, stream);  // counts + cursor

  router_kernel<<<dim3(T_TOK), dim3(256), 0, stream>>>(x, gate_w, sel, selw, counts, x_bf);
  scatter_kernel<<<dim3(48), dim3(256), 0, stream>>>(sel, selw, counts, cursor,
                                                     tok_of_row, coef_of_row, row_of_tok);

  // R16 grid: x=nt (fastest, shares gathered A-tile across 16 blocks), y=rt;
  // z=0: W2 cvt blocks (overlap gemm1's idle BW); z=1..17: experts
  gemm1_kernel<<<dim3(16, 32, 18), dim3(256), 0, stream>>>(
      x_bf, w1, sg_w, b1, sg_b, tok_of_row, counts, abuf, w2, sd_w, W2cat);

  gemm2_kernel<<<dim3(16, 32, 17), dim3(256), 0, stream>>>(
      abuf, W2cat, tok_of_row, coef_of_row, counts, y, out);

  combine_kernel<<<dim3(T_TOK), dim3(256), 0, stream>>>(out, y, row_of_tok);
}